// Round 17
// baseline (400.004 us; speedup 1.0000x reference)
//
#include <hip/hip_runtime.h>
#include <stdint.h>

// SpikingLinearLayer: 20-step LIF over [512 batch, 2048 out] driven by
// binary (10% dense) input spikes x[20,512,2048] through W[2048,2048].
//
// EXACT i8-MFMA path (validated absmax 0.0 in R14/R15/R16): W -> 4
// limbs of q = round(W*2^31) (3 balanced base-256 digits + top); x in
// {0,1}. C = (sum_j 256^j C_j) * 2^-31, C_j exact int32 i8 GEMMs;
// int64 recombine + fp64 scale exact. QUANTIZATION FROZEN.
//
// R15: double-buffer DMA -> gemm 160us @47% MfmaUtil (4 blocks/CU).
// R16: limb-pair blocks (175 OP/B, -25% bytes) -> 168us @45% -- NEUTRAL:
// intensity gain cancelled by delivered-BW loss. Accounting: per-kc wall
// 2520 cyc, MFMA 1170 (=46% ✓), staged delivery only ~19 B/cyc/CU
// (~4.9 TB/s) => the gemm is LLC-delivery-bound: xq/wq re-reads come
// from Infinity Cache (blocks with no XCD-local reuse ordering), not L2.
//
// R17: XCD-aware grid reorder ONLY. bid = [mt_hi][sg=pair*ntc][mt_lo:3]
// (mt_lo fastest => same-XCD co-resident blocks share 3 A-tiles x32
// blocks and 32 B-tiles x3 blocks; per-XCD per-kc working set ~0.5 MB
// fits L2). LLC->L2 traffic ~14x down; staging becomes L2-served and
// overlaps inside the 1170-cyc compute window. Math untouched.

#define STEPS  20
#define BATCH  512
#define DIM    2048

// ---- ws layout (MFMA path)
#define XQ_OFF   0ULL
#define WQ_OFF   20971520ULL          // xq: 80*32*8192
#define C_OFF    37748736ULL          // + wq: 4*16*32*8192

#define GLOBAL_AS __attribute__((address_space(1)))
#define LDS_AS    __attribute__((address_space(3)))

typedef int v4i  __attribute__((ext_vector_type(4)));
typedef int v16i __attribute__((ext_vector_type(16)));

// ============================ MFMA path ============================

// xq[mt<80][kc<32][w<4][mm<128][16] : byte = (x[m][k]!=0)
//   m = mt*128+mm, k = kc*64 + w*16 + j   (m = t*512+b natural order)
__global__ __launch_bounds__(256)
void prep_x_kernel(const float* __restrict__ x, char* __restrict__ wsb)
{
    const int bid = blockIdx.x;           // bid = mt*32 + kc
    const int kc = bid & 31, mt = bid >> 5;
    const int tid = threadIdx.x;
    char* outb = wsb + (size_t)bid * 8192;
#pragma unroll
    for (int it = 0; it < 8; ++it) {
        const int idx = it * 256 + tid;
        const int mm = idx >> 4;
        const int kk4 = (idx & 15) << 2;
        const float4 v = *reinterpret_cast<const float4*>(
            x + (size_t)(mt * 128 + mm) * DIM + kc * 64 + kk4);
        uchar4 o;
        o.x = (v.x != 0.0f); o.y = (v.y != 0.0f);
        o.z = (v.z != 0.0f); o.w = (v.w != 0.0f);
        *reinterpret_cast<uchar4*>(
            outb + (((kk4 >> 4) * 128 + mm) << 4) + (kk4 & 15)) = o;
    }
}

// wq[limb<4][nt<16][kc<32][w<4][nn<128][16] :
//   byte = digit_limb(round(W[o][k]*2^31)), o = nt*128+nn, k = kc*64+w*16+j
__global__ __launch_bounds__(256)
void prep_w_kernel(const float* __restrict__ W, char* __restrict__ wsb)
{
    const int bid = blockIdx.x;           // bid = nt*32 + kc
    const int kc = bid & 31, nt = bid >> 5;
    const int tid = threadIdx.x;
    char* wqb = wsb + WQ_OFF;
#pragma unroll
    for (int it = 0; it < 8; ++it) {
        const int idx = it * 256 + tid;
        const int nn = idx >> 4;
        const int kk4 = (idx & 15) << 2;
        const float4 v = *reinterpret_cast<const float4*>(
            W + (size_t)(nt * 128 + nn) * DIM + kc * 64 + kk4);
        int dg[4][4];
        const float* vp = &v.x;
#pragma unroll
        for (int c = 0; c < 4; ++c) {
            long long q = __double2ll_rn((double)vp[c] * 2147483648.0);
#pragma unroll
            for (int j = 0; j < 3; ++j) {
                int d = (int)(q & 255);
                if (d >= 128) d -= 256;        // balanced digit
                dg[c][j] = d;
                q = (q - d) >> 8;
            }
            dg[c][3] = (int)q;                 // |.| <= ~97 for |W| < 0.76
        }
        const size_t sub = (size_t)(((kk4 >> 4) * 128 + nn) << 4) + (kk4 & 15);
#pragma unroll
        for (int j = 0; j < 4; ++j) {
            uchar4 o;
            o.x = (unsigned char)(dg[0][j] & 255);
            o.y = (unsigned char)(dg[1][j] & 255);
            o.z = (unsigned char)(dg[2][j] & 255);
            o.w = (unsigned char)(dg[3][j] & 255);
            *reinterpret_cast<uchar4*>(
                wqb + ((size_t)((j * 16 + nt) * 32 + kc)) * 8192 + sub) = o;
        }
    }
}

// Limb-pair GEMM: block computes 128x128 tile for TWO limbs (2p, 2p+1)
// sharing the staged A tile. 4 waves, each 64x64 per limb (2x2 of
// 32x32x32 i8 mfma x 2 limbs = 16 mfma/wave/kc). Double-buffered DMA.
// R17 grid: bid = [mt_hi][sg = pair*ntc_cnt + ntc][mt_lo(3b)] --
// mt_lo fastest so same-XCD co-resident blocks share A- and B-tiles
// in their XCD L2 (the %8 XCD heuristic; speed-only, G16-safe).
__global__ __launch_bounds__(256, 2)
void gemm_i8_kernel(const char* __restrict__ wsb_c, short* __restrict__ cp,
                    int nt0, int ntc_cnt, int no)
{
    __shared__ __align__(16) char lds[2][24576];  // [buf][A 8K|B0 8K|B1 8K]

    const int bid = blockIdx.x;
    const int SG = 2 * ntc_cnt;           // sharegroups (pair x ntc)
    const int mt_lo = bid & 7;
    const int rest = bid >> 3;
    const int sg = rest % SG;
    const int mt_hi = rest / SG;
    const int mt = mt_hi * 8 + mt_lo;
    const int ntc = sg % ntc_cnt;
    const int pair = sg / ntc_cnt;        // 0..1 -> limbs {2p, 2p+1}

    const int tid = threadIdx.x;
    const int lane = tid & 63, w = tid >> 6;
    const int kh = lane >> 5, ln = lane & 31;
    const int wy = w & 1, wx = w >> 1;

    const char* abase = wsb_c + XQ_OFF + ((size_t)mt * 32) * 8192;
    const char* bbase0 = wsb_c + WQ_OFF
        + ((size_t)(((pair * 2 + 0) * 16 + nt0 + ntc) * 32)) * 8192;
    const char* bbase1 = wsb_c + WQ_OFF
        + ((size_t)(((pair * 2 + 1) * 16 + nt0 + ntc) * 32)) * 8192;

    const int aoff = ((kh * 128) + wy * 64 + ln) << 4;
    const int boff = ((kh * 128) + wx * 64 + ln) << 4;
    const int stg = (w * 2) * 1024 + (lane << 4);   // this wave's DMA slot

    v16i acc0_00, acc0_01, acc0_10, acc0_11;
    v16i acc1_00, acc1_01, acc1_10, acc1_11;
#pragma unroll
    for (int r = 0; r < 16; ++r) {
        acc0_00[r] = 0; acc0_01[r] = 0; acc0_10[r] = 0; acc0_11[r] = 0;
        acc1_00[r] = 0; acc1_01[r] = 0; acc1_10[r] = 0; acc1_11[r] = 0;
    }

    LDS_AS char* l0 = (LDS_AS char*)(&lds[0][0]);
    LDS_AS char* l1 = (LDS_AS char*)(&lds[1][0]);

    // prologue: stage kc=0 into buf0 (A, B0, B1)
#pragma unroll
    for (int i = 0; i < 2; ++i) {
        __builtin_amdgcn_global_load_lds(
            (const GLOBAL_AS void*)(abase + stg + i * 1024),
            (LDS_AS void*)(l0 + (w * 2 + i) * 1024), 16, 0, 0);
        __builtin_amdgcn_global_load_lds(
            (const GLOBAL_AS void*)(bbase0 + stg + i * 1024),
            (LDS_AS void*)(l0 + 8192 + (w * 2 + i) * 1024), 16, 0, 0);
        __builtin_amdgcn_global_load_lds(
            (const GLOBAL_AS void*)(bbase1 + stg + i * 1024),
            (LDS_AS void*)(l0 + 16384 + (w * 2 + i) * 1024), 16, 0, 0);
    }

    for (int kc = 0; kc < 32; ++kc) {
        __syncthreads();   // drains prefetch for kc (issued one iter ago)
        const int cur = kc & 1;
        if (kc + 1 < 32) {
            LDS_AS char* ldst = (kc & 1) ? l0 : l1;
            const size_t src = (size_t)(kc + 1) * 8192 + stg;
#pragma unroll
            for (int i = 0; i < 2; ++i) {
                __builtin_amdgcn_global_load_lds(
                    (const GLOBAL_AS void*)(abase + src + i * 1024),
                    (LDS_AS void*)(ldst + (w * 2 + i) * 1024), 16, 0, 0);
                __builtin_amdgcn_global_load_lds(
                    (const GLOBAL_AS void*)(bbase0 + src + i * 1024),
                    (LDS_AS void*)(ldst + 8192 + (w * 2 + i) * 1024), 16, 0, 0);
                __builtin_amdgcn_global_load_lds(
                    (const GLOBAL_AS void*)(bbase1 + src + i * 1024),
                    (LDS_AS void*)(ldst + 16384 + (w * 2 + i) * 1024), 16, 0, 0);
            }
        }
        const char* A  = &lds[cur][0];
        const char* B0 = &lds[cur][8192];
        const char* B1 = &lds[cur][16384];
#pragma unroll
        for (int s = 0; s < 2; ++s) {
            const v4i a0  = *reinterpret_cast<const v4i*>(A  + aoff + s * 4096);
            const v4i a1  = *reinterpret_cast<const v4i*>(A  + aoff + 512 + s * 4096);
            const v4i b00 = *reinterpret_cast<const v4i*>(B0 + boff + s * 4096);
            const v4i b01 = *reinterpret_cast<const v4i*>(B0 + boff + 512 + s * 4096);
            const v4i b10 = *reinterpret_cast<const v4i*>(B1 + boff + s * 4096);
            const v4i b11 = *reinterpret_cast<const v4i*>(B1 + boff + 512 + s * 4096);
            acc0_00 = __builtin_amdgcn_mfma_i32_32x32x32_i8(a0, b00, acc0_00, 0, 0, 0);
            acc0_01 = __builtin_amdgcn_mfma_i32_32x32x32_i8(a0, b01, acc0_01, 0, 0, 0);
            acc0_10 = __builtin_amdgcn_mfma_i32_32x32x32_i8(a1, b00, acc0_10, 0, 0, 0);
            acc0_11 = __builtin_amdgcn_mfma_i32_32x32x32_i8(a1, b01, acc0_11, 0, 0, 0);
            acc1_00 = __builtin_amdgcn_mfma_i32_32x32x32_i8(a0, b10, acc1_00, 0, 0, 0);
            acc1_01 = __builtin_amdgcn_mfma_i32_32x32x32_i8(a0, b11, acc1_01, 0, 0, 0);
            acc1_10 = __builtin_amdgcn_mfma_i32_32x32x32_i8(a1, b10, acc1_10, 0, 0, 0);
            acc1_11 = __builtin_amdgcn_mfma_i32_32x32x32_i8(a1, b11, acc1_11, 0, 0, 0);
        }
    }

    // epilogue: C/D layout col=lane&31, row=(r&3)+8*(r>>2)+4*(lane>>5)
    const size_t plane = (size_t)10240 * no;
    short* cpl0 = cp + (size_t)(pair * 2 + 0) * plane;
    short* cpl1 = cp + (size_t)(pair * 2 + 1) * plane;
    const int m_base = mt * 128 + wy * 64;
    const int o_base = ntc * 128 + wx * 64 + ln;
#pragma unroll
    for (int r = 0; r < 16; ++r) {
        const int row = (r & 3) + ((r >> 2) << 3) + (kh << 2);
        const size_t m0 = (size_t)(m_base + row) * no;
        const size_t m1 = (size_t)(m_base + 32 + row) * no;
        cpl0[m0 + o_base]      = (short)acc0_00[r];
        cpl0[m0 + o_base + 32] = (short)acc0_01[r];
        cpl0[m1 + o_base]      = (short)acc0_10[r];
        cpl0[m1 + o_base + 32] = (short)acc0_11[r];
        cpl1[m0 + o_base]      = (short)acc1_00[r];
        cpl1[m0 + o_base + 32] = (short)acc1_01[r];
        cpl1[m1 + o_base]      = (short)acc1_10[r];
        cpl1[m1 + o_base + 32] = (short)acc1_11[r];
    }
}

// LIF scan for one o-chunk: exact int64 recombine of 4 int16 limb
// planes, fp64 scale by 2^-31 (exact), reference op order.
__global__ __launch_bounds__(256)
void lif_kernel(const short* __restrict__ cp, float* __restrict__ out,
                int o0, int no, int shift)
{
    const int g = blockIdx.x * 256 + threadIdx.x;
    const int b = g >> shift;                  // shift = log2(no/4)
    const int oq = g & ((1 << shift) - 1);
    const int o_local = oq << 2;
    const size_t plane = (size_t)10240 * no;

    const double A_M = 1.0 - 1.0 / 20.0;   // 0.95
    const double DTM = 1.0 / 20.0;         // 0.05
    const double A_S = 1.0 - 1.0 / 5.0;    // 0.8
    double V[4], I[4];
#pragma unroll
    for (int u = 0; u < 4; ++u) { V[u] = 0.0; I[u] = 0.0; }

#pragma unroll
    for (int t = 0; t < STEPS; ++t) {
        const size_t ix = (size_t)(t * BATCH + b) * no + o_local;
        const short4 c0 = *reinterpret_cast<const short4*>(cp + ix);
        const short4 c1 = *reinterpret_cast<const short4*>(cp + plane + ix);
        const short4 c2 = *reinterpret_cast<const short4*>(cp + 2 * plane + ix);
        const short4 c3 = *reinterpret_cast<const short4*>(cp + 3 * plane + ix);
        const short* p0 = &c0.x; const short* p1 = &c1.x;
        const short* p2 = &c2.x; const short* p3 = &c3.x;
        float4 s;
        float* sp = &s.x;
#pragma unroll
        for (int u = 0; u < 4; ++u) {
            const long long tot = (long long)p0[u]
                + ((long long)p1[u] << 8)
                + ((long long)p2[u] << 16)
                + ((long long)p3[u] << 24);
            const double val = (double)tot * 4.6566128730773926e-10; // 2^-31
            V[u] = A_M * V[u] + DTM * I[u];
            float sv = 0.0f;
            if (V[u] >= 1.0) { sv = 1.0f; V[u] = 0.0; }
            sp[u] = sv;
            I[u] = A_S * I[u] + val;
        }
        *reinterpret_cast<float4*>(
            out + (size_t)(t * BATCH + b) * DIM + o0 + o_local) = s;
    }
}

// ===================== fallback (R10 sparse path) =====================

#define B_TILE 2
#define O_TILE 256
#define NT     512
#define KT     32
#define NSLAB  (DIM / KT)
#define ROWB   1024

__global__ __launch_bounds__(256)
void transpose_kernel(const float* __restrict__ W, float* __restrict__ WT)
{
    __shared__ float tile[64][65];
    const int tid = threadIdx.x;
    const int c4 = (tid & 15) * 4;
    const int rr = tid >> 4;
    const int k0 = blockIdx.x * 64, o0 = blockIdx.y * 64;
#pragma unroll
    for (int i = 0; i < 64; i += 16) {
        const float4 v = *reinterpret_cast<const float4*>(
            W + (size_t)(o0 + rr + i) * DIM + k0 + c4);
        tile[c4 + 0][rr + i] = v.x;
        tile[c4 + 1][rr + i] = v.y;
        tile[c4 + 2][rr + i] = v.z;
        tile[c4 + 3][rr + i] = v.w;
    }
    __syncthreads();
#pragma unroll
    for (int i = 0; i < 64; i += 16) {
        float4 v;
        v.x = tile[rr + i][c4 + 0];
        v.y = tile[rr + i][c4 + 1];
        v.z = tile[rr + i][c4 + 2];
        v.w = tile[rr + i][c4 + 3];
        *reinterpret_cast<float4*>(
            WT + (size_t)(k0 + rr + i) * DIM + o0 + c4) = v;
    }
}

__global__ __launch_bounds__(NT, 6)
void snn_lif_kernel(const float* __restrict__ x,
                    const float* __restrict__ WT,
                    float* __restrict__ out)
{
    __shared__ __align__(16) float wlds[(KT * ROWB) / 4];

    const int tid  = threadIdx.x;
    const int lane = tid & 63;
    const int w    = tid >> 6;
    const int bl   = w & 1;
    const int tq   = w >> 1;
    const int o_blk = blockIdx.x & 7;
    const int b_blk = blockIdx.x >> 3;
    const int b  = b_blk * B_TILE + bl;
    const int o0 = o_blk * O_TILE;

    double acc[5][4];
#pragma unroll
    for (int tt = 0; tt < 5; ++tt)
#pragma unroll
        for (int u = 0; u < 4; ++u) acc[tt][u] = 0.0;

    const int kl = lane & 31;
    float xr[5];
#pragma unroll
    for (int m = 0; m < 5; ++m)
        xr[m] = x[((size_t)(tq * 5 + m) * BATCH + b) * DIM + kl];

    const char*   gb   = (const char*)wlds + (lane << 4);
    LDS_AS char*  ldsb = (LDS_AS char*)wlds;
    const float*  wsrc = WT + o0 + (lane << 2);

    for (int kt = 0; kt < NSLAB; ++kt) {
        const int k0 = kt * KT;
        __syncthreads();
#pragma unroll
        for (int it = 0; it < 4; ++it) {
            const int r = w + it * 8;
            __builtin_amdgcn_global_load_lds(
                (const GLOBAL_AS void*)(wsrc + (size_t)(k0 + r) * DIM),
                (LDS_AS void*)(ldsb + r * ROWB), 16, 0, 0);
        }
        unsigned mk[5];
#pragma unroll
        for (int m = 0; m < 5; ++m)
            mk[m] = (unsigned)__ballot(xr[m] != 0.0f);
        __syncthreads();
        if (kt + 1 < NSLAB) {
            const int k1 = k0 + KT;
#pragma unroll
            for (int m = 0; m < 5; ++m)
                xr[m] = x[((size_t)(tq * 5 + m) * BATCH + b) * DIM + k1 + kl];
        }
#pragma unroll
        for (int m = 0; m < 5; ++m) {
            unsigned msk = mk[m];
            while (msk & (msk - 1)) {
                const int r0 = __builtin_ctz(msk); msk &= msk - 1;
                const int r1 = __builtin_ctz(msk); msk &= msk - 1;
                const float4 va = *reinterpret_cast<const float4*>(gb + (r0 << 10));
                const float4 vb = *reinterpret_cast<const float4*>(gb + (r1 << 10));
                acc[m][0] += (double)va.x; acc[m][1] += (double)va.y;
                acc[m][2] += (double)va.z; acc[m][3] += (double)va.w;
                acc[m][0] += (double)vb.x; acc[m][1] += (double)vb.y;
                acc[m][2] += (double)vb.z; acc[m][3] += (double)vb.w;
            }
            if (msk) {
                const int r = __builtin_ctz(msk);
                const float4 wv = *reinterpret_cast<const float4*>(gb + (r << 10));
                acc[m][0] += (double)wv.x; acc[m][1] += (double)wv.y;
                acc[m][2] += (double)wv.z; acc[m][3] += (double)wv.w;
            }
        }
    }

    const double A_M = 1.0 - 1.0 / 20.0;
    const double DTM = 1.0 / 20.0;
    const double A_S = 1.0 - 1.0 / 5.0;

    __syncthreads();
    double2* hand = reinterpret_cast<double2*>(wlds);
    const int hbase = bl * 256 + (lane << 2);
    const size_t obase = (size_t)o0 + (lane << 2);

    for (int seg = 0; seg < 4; ++seg) {
        if (tq == seg) {
            double V[4], I[4];
            if (seg == 0) {
#pragma unroll
                for (int u = 0; u < 4; ++u) { V[u] = 0.0; I[u] = 0.0; }
            } else {
#pragma unroll
                for (int u = 0; u < 4; ++u) {
                    const double2 h = hand[hbase + u];
                    V[u] = h.x; I[u] = h.y;
                }
            }
#pragma unroll
            for (int tt = 0; tt < 5; ++tt) {
                const int t = seg * 5 + tt;
                float4 s;
                float* sp = &s.x;
#pragma unroll
                for (int u = 0; u < 4; ++u) {
                    V[u] = A_M * V[u] + DTM * I[u];
                    float sv = 0.0f;
                    if (V[u] >= 1.0) { sv = 1.0f; V[u] = 0.0; }
                    sp[u] = sv;
                    I[u] = A_S * I[u] + acc[tt][u];
                }
                *reinterpret_cast<float4*>(
                    out + ((size_t)t * BATCH + b) * DIM + obase) = s;
            }
            if (seg < 3) {
#pragma unroll
                for (int u = 0; u < 4; ++u)
                    hand[hbase + u] = make_double2(V[u], I[u]);
            }
        }
        __syncthreads();
    }
}

// ============================== host ==============================

extern "C" void kernel_launch(void* const* d_in, const int* in_sizes, int n_in,
                              void* d_out, int out_size, void* d_ws, size_t ws_size,
                              hipStream_t stream) {
    const float* x = (const float*)d_in[0];   // [20, 512, 2048] spikes
    const float* W = (const float*)d_in[1];   // [2048, 2048]
    float* out = (float*)d_out;               // [20, 512, 2048]
    char* wsb = (char*)d_ws;

    // choose the largest o-chunk whose int16 C planes fit in ws
    // need(no) = C_OFF + 4 * 10240 * no * 2 bytes
    int no = 0, shift = 0;
    if      (ws_size >= C_OFF + 81920ULL * 2048) { no = 2048; shift = 9; }
    else if (ws_size >= C_OFF + 81920ULL * 1024) { no = 1024; shift = 8; }
    else if (ws_size >= C_OFF + 81920ULL * 512)  { no = 512;  shift = 7; }
    else if (ws_size >= C_OFF + 81920ULL * 256)  { no = 256;  shift = 6; }
    else if (ws_size >= C_OFF + 81920ULL * 128)  { no = 128;  shift = 5; }

    if (no) {
        // exact i8-MFMA path (limb-pair gemm, XCD-swizzled grid)
        prep_x_kernel<<<2560, 256, 0, stream>>>(x, wsb);
        prep_w_kernel<<<512, 256, 0, stream>>>(W, wsb);
        short* cp = (short*)(wsb + C_OFF);
        const int ntc_cnt = no / 128;
        for (int nt0 = 0; nt0 < 16; nt0 += ntc_cnt) {
            gemm_i8_kernel<<<2 * ntc_cnt * 80, 256, 0, stream>>>(
                (const char*)wsb, cp, nt0, ntc_cnt, no);
            lif_kernel<<<no / 2, 256, 0, stream>>>(
                (const short*)cp, out, nt0 * 128, no, shift);
        }
    } else {
        // fallback: R10 sparse-gather pipeline (known-good, 580 us)
        float* WT = (float*)d_ws;
        dim3 tb(256);
        dim3 tg(DIM / 64, DIM / 64);
        transpose_kernel<<<tg, tb, 0, stream>>>(W, WT);
        const int grid = (BATCH / B_TILE) * (DIM / O_TILE);
        snn_lif_kernel<<<grid, NT, 0, stream>>>(x, WT, out);
    }
}

// Round 18
// 338.019 us; speedup vs baseline: 1.1834x; 1.1834x over previous
//
#include <hip/hip_runtime.h>
#include <stdint.h>

// SpikingLinearLayer: 20-step LIF over [512 batch, 2048 out] driven by
// binary (10% dense) input spikes x[20,512,2048] through W[2048,2048].
//
// EXACT i8-MFMA path (validated absmax 0.0 in R14-R17): W -> 4 limbs of
// q = round(W*2^31) (3 balanced base-256 digits + top); x in {0,1}.
// C = (sum_j 256^j C_j) * 2^-31, C_j exact int32 i8 GEMMs; int64
// recombine + fp64 scale exact. QUANTIZATION FROZEN: 3-limb analysis
// gives per-V error sigma ~7e-8 vs expected min spike margin ~2.5e-8
// over 20M element-steps => O(1) flips. Do not reduce limbs.
//
// R15 (best gemm): single-limb blocks, double-buffered DMA prefetch,
// 4 blocks/CU -> 160us total gemm @ MfmaUtil 47%, delivery ~16.4 TB/s.
// R16 (neutral): limb-pair intensity +33% cancelled by MLP loss.
// R17 (reverted): mt_lo-fastest swizzle separated B-tile sharers in
// dispatch time -> LLC evicted wq between uses -> FETCH 146->620 MB,
// gemm 213us. Lesson: dispatch-order temporal locality in LLC beats
// XCD-L2 placement; keep B-tile sharers consecutive (mt fastest),
// small xq (20 MB) stays LLC-resident.
//
// R18: R15 gemm verbatim + single-shot no=2048 (1 gemm + 1 lif + 2
// preps = 4 dispatches, was 11) to harvest ~90us of launch gaps/tails.

#define STEPS  20
#define BATCH  512
#define DIM    2048

// ---- ws layout (MFMA path)
#define XQ_OFF   0ULL
#define WQ_OFF   20971520ULL          // xq: 80*32*8192
#define C_OFF    37748736ULL          // + wq: 4*16*32*8192

#define GLOBAL_AS __attribute__((address_space(1)))
#define LDS_AS    __attribute__((address_space(3)))

typedef int v4i  __attribute__((ext_vector_type(4)));
typedef int v16i __attribute__((ext_vector_type(16)));

// ============================ MFMA path ============================

// xq[mt<80][kc<32][w<4][mm<128][16] : byte = (x[m][k]!=0)
//   m = mt*128+mm, k = kc*64 + w*16 + j   (m = t*512+b natural order)
__global__ __launch_bounds__(256)
void prep_x_kernel(const float* __restrict__ x, char* __restrict__ wsb)
{
    const int bid = blockIdx.x;           // bid = mt*32 + kc
    const int kc = bid & 31, mt = bid >> 5;
    const int tid = threadIdx.x;
    char* outb = wsb + (size_t)bid * 8192;
#pragma unroll
    for (int it = 0; it < 8; ++it) {
        const int idx = it * 256 + tid;
        const int mm = idx >> 4;
        const int kk4 = (idx & 15) << 2;
        const float4 v = *reinterpret_cast<const float4*>(
            x + (size_t)(mt * 128 + mm) * DIM + kc * 64 + kk4);
        uchar4 o;
        o.x = (v.x != 0.0f); o.y = (v.y != 0.0f);
        o.z = (v.z != 0.0f); o.w = (v.w != 0.0f);
        *reinterpret_cast<uchar4*>(
            outb + (((kk4 >> 4) * 128 + mm) << 4) + (kk4 & 15)) = o;
    }
}

// wq[limb<4][nt<16][kc<32][w<4][nn<128][16] :
//   byte = digit_limb(round(W[o][k]*2^31)), o = nt*128+nn, k = kc*64+w*16+j
__global__ __launch_bounds__(256)
void prep_w_kernel(const float* __restrict__ W, char* __restrict__ wsb)
{
    const int bid = blockIdx.x;           // bid = nt*32 + kc
    const int kc = bid & 31, nt = bid >> 5;
    const int tid = threadIdx.x;
    char* wqb = wsb + WQ_OFF;
#pragma unroll
    for (int it = 0; it < 8; ++it) {
        const int idx = it * 256 + tid;
        const int nn = idx >> 4;
        const int kk4 = (idx & 15) << 2;
        const float4 v = *reinterpret_cast<const float4*>(
            W + (size_t)(nt * 128 + nn) * DIM + kc * 64 + kk4);
        int dg[4][4];
        const float* vp = &v.x;
#pragma unroll
        for (int c = 0; c < 4; ++c) {
            long long q = __double2ll_rn((double)vp[c] * 2147483648.0);
#pragma unroll
            for (int j = 0; j < 3; ++j) {
                int d = (int)(q & 255);
                if (d >= 128) d -= 256;        // balanced digit
                dg[c][j] = d;
                q = (q - d) >> 8;
            }
            dg[c][3] = (int)q;                 // |.| <= ~97 for |W| < 0.76
        }
        const size_t sub = (size_t)(((kk4 >> 4) * 128 + nn) << 4) + (kk4 & 15);
#pragma unroll
        for (int j = 0; j < 4; ++j) {
            uchar4 o;
            o.x = (unsigned char)(dg[0][j] & 255);
            o.y = (unsigned char)(dg[1][j] & 255);
            o.z = (unsigned char)(dg[2][j] & 255);
            o.w = (unsigned char)(dg[3][j] & 255);
            *reinterpret_cast<uchar4*>(
                wqb + ((size_t)((j * 16 + nt) * 32 + kc)) * 8192 + sub) = o;
        }
    }
}

// C_j[m][o_local] int16 planes for one o-chunk of width NO.
// Block tile 128x128, 4 waves each 64x64 (2x2 of 32x32x32 i8 mfma).
// KC=64, double-buffered global_load_lds prefetch, 1 barrier per kc.
// Grid: limb slow, ntc mid, mt FAST (B-tile sharers consecutive in
// dispatch order -> B read from HBM once; xq 20 MB stays LLC-resident).
__global__ __launch_bounds__(256, 4)
void gemm_i8_kernel(const char* __restrict__ wsb_c, short* __restrict__ cp,
                    int nt0, int ntc_cnt, int no)
{
    __shared__ __align__(16) char lds[2][16384];   // [buf][A 8K | B 8K]

    const int bid = blockIdx.x;           // mt fastest, ntc mid, limb slow
    const int mt = bid % 80;
    const int rest = bid / 80;
    const int ntc = rest % ntc_cnt;
    const int limb = rest / ntc_cnt;

    const int tid = threadIdx.x;
    const int lane = tid & 63, w = tid >> 6;
    const int kh = lane >> 5, ln = lane & 31;
    const int wy = w & 1, wx = w >> 1;

    const char* abase = wsb_c + XQ_OFF + ((size_t)mt * 32) * 8192;
    const char* bbase = wsb_c + WQ_OFF
        + ((size_t)((limb * 16 + nt0 + ntc) * 32)) * 8192;

    const int aoff = ((kh * 128) + wy * 64 + ln) << 4;
    const int boff = ((kh * 128) + wx * 64 + ln) << 4;
    const int stg = (w * 2) * 1024 + (lane << 4);   // this wave's DMA slot

    v16i acc00, acc01, acc10, acc11;
#pragma unroll
    for (int r = 0; r < 16; ++r) {
        acc00[r] = 0; acc01[r] = 0; acc10[r] = 0; acc11[r] = 0;
    }

    LDS_AS char* l0 = (LDS_AS char*)(&lds[0][0]);
    LDS_AS char* l1 = (LDS_AS char*)(&lds[1][0]);

    // prologue: stage kc=0 into buf0 (cold, zero flight -- once only)
#pragma unroll
    for (int i = 0; i < 2; ++i) {
        __builtin_amdgcn_global_load_lds(
            (const GLOBAL_AS void*)(abase + stg + i * 1024),
            (LDS_AS void*)(l0 + (w * 2 + i) * 1024), 16, 0, 0);
        __builtin_amdgcn_global_load_lds(
            (const GLOBAL_AS void*)(bbase + stg + i * 1024),
            (LDS_AS void*)(l0 + 8192 + (w * 2 + i) * 1024), 16, 0, 0);
    }

    for (int kc = 0; kc < 32; ++kc) {
        __syncthreads();   // drains prefetch for kc (issued one iter ago)
        const int cur = kc & 1;
        if (kc + 1 < 32) {
            // prefetch kc+1 into the other buffer: a full iteration of
            // flight before the next barrier's vmcnt(0) drain.
            LDS_AS char* ldst = (kc & 1) ? l0 : l1;
            const size_t src = (size_t)(kc + 1) * 8192 + stg;
#pragma unroll
            for (int i = 0; i < 2; ++i) {
                __builtin_amdgcn_global_load_lds(
                    (const GLOBAL_AS void*)(abase + src + i * 1024),
                    (LDS_AS void*)(ldst + (w * 2 + i) * 1024), 16, 0, 0);
                __builtin_amdgcn_global_load_lds(
                    (const GLOBAL_AS void*)(bbase + src + i * 1024),
                    (LDS_AS void*)(ldst + 8192 + (w * 2 + i) * 1024), 16, 0, 0);
            }
        }
        const char* A = &lds[cur][0];
        const char* B = &lds[cur][8192];
#pragma unroll
        for (int s = 0; s < 2; ++s) {
            const v4i a0 = *reinterpret_cast<const v4i*>(A + aoff + s * 4096);
            const v4i a1 = *reinterpret_cast<const v4i*>(A + aoff + 512 + s * 4096);
            const v4i b0 = *reinterpret_cast<const v4i*>(B + boff + s * 4096);
            const v4i b1 = *reinterpret_cast<const v4i*>(B + boff + 512 + s * 4096);
            acc00 = __builtin_amdgcn_mfma_i32_32x32x32_i8(a0, b0, acc00, 0, 0, 0);
            acc01 = __builtin_amdgcn_mfma_i32_32x32x32_i8(a0, b1, acc01, 0, 0, 0);
            acc10 = __builtin_amdgcn_mfma_i32_32x32x32_i8(a1, b0, acc10, 0, 0, 0);
            acc11 = __builtin_amdgcn_mfma_i32_32x32x32_i8(a1, b1, acc11, 0, 0, 0);
        }
    }

    // epilogue: C/D layout col=lane&31, row=(r&3)+8*(r>>2)+4*(lane>>5);
    // int16 stores (|C_j| <= ~8.5k max realistic, 31 sigma to overflow)
    short* cpl = cp + (size_t)limb * 10240 * no;
    const int m_base = mt * 128 + wy * 64;
    const int o_base = ntc * 128 + wx * 64 + ln;
#pragma unroll
    for (int r = 0; r < 16; ++r) {
        const int row = (r & 3) + ((r >> 2) << 3) + (kh << 2);
        const size_t m0 = (size_t)(m_base + row) * no;
        const size_t m1 = (size_t)(m_base + 32 + row) * no;
        cpl[m0 + o_base]      = (short)acc00[r];
        cpl[m0 + o_base + 32] = (short)acc01[r];
        cpl[m1 + o_base]      = (short)acc10[r];
        cpl[m1 + o_base + 32] = (short)acc11[r];
    }
}

// LIF scan for one o-chunk: exact int64 recombine of 4 int16 limb
// planes, fp64 scale by 2^-31 (exact), reference op order.
__global__ __launch_bounds__(256)
void lif_kernel(const short* __restrict__ cp, float* __restrict__ out,
                int o0, int no, int shift)
{
    const int g = blockIdx.x * 256 + threadIdx.x;
    const int b = g >> shift;                  // shift = log2(no/4)
    const int oq = g & ((1 << shift) - 1);
    const int o_local = oq << 2;
    const size_t plane = (size_t)10240 * no;

    const double A_M = 1.0 - 1.0 / 20.0;   // 0.95
    const double DTM = 1.0 / 20.0;         // 0.05
    const double A_S = 1.0 - 1.0 / 5.0;    // 0.8
    double V[4], I[4];
#pragma unroll
    for (int u = 0; u < 4; ++u) { V[u] = 0.0; I[u] = 0.0; }

#pragma unroll
    for (int t = 0; t < STEPS; ++t) {
        const size_t ix = (size_t)(t * BATCH + b) * no + o_local;
        const short4 c0 = *reinterpret_cast<const short4*>(cp + ix);
        const short4 c1 = *reinterpret_cast<const short4*>(cp + plane + ix);
        const short4 c2 = *reinterpret_cast<const short4*>(cp + 2 * plane + ix);
        const short4 c3 = *reinterpret_cast<const short4*>(cp + 3 * plane + ix);
        const short* p0 = &c0.x; const short* p1 = &c1.x;
        const short* p2 = &c2.x; const short* p3 = &c3.x;
        float4 s;
        float* sp = &s.x;
#pragma unroll
        for (int u = 0; u < 4; ++u) {
            const long long tot = (long long)p0[u]
                + ((long long)p1[u] << 8)
                + ((long long)p2[u] << 16)
                + ((long long)p3[u] << 24);
            const double val = (double)tot * 4.6566128730773926e-10; // 2^-31
            V[u] = A_M * V[u] + DTM * I[u];
            float sv = 0.0f;
            if (V[u] >= 1.0) { sv = 1.0f; V[u] = 0.0; }
            sp[u] = sv;
            I[u] = A_S * I[u] + val;
        }
        *reinterpret_cast<float4*>(
            out + (size_t)(t * BATCH + b) * DIM + o0 + o_local) = s;
    }
}

// ===================== fallback (R10 sparse path) =====================

#define B_TILE 2
#define O_TILE 256
#define NT     512
#define KT     32
#define NSLAB  (DIM / KT)
#define ROWB   1024

__global__ __launch_bounds__(256)
void transpose_kernel(const float* __restrict__ W, float* __restrict__ WT)
{
    __shared__ float tile[64][65];
    const int tid = threadIdx.x;
    const int c4 = (tid & 15) * 4;
    const int rr = tid >> 4;
    const int k0 = blockIdx.x * 64, o0 = blockIdx.y * 64;
#pragma unroll
    for (int i = 0; i < 64; i += 16) {
        const float4 v = *reinterpret_cast<const float4*>(
            W + (size_t)(o0 + rr + i) * DIM + k0 + c4);
        tile[c4 + 0][rr + i] = v.x;
        tile[c4 + 1][rr + i] = v.y;
        tile[c4 + 2][rr + i] = v.z;
        tile[c4 + 3][rr + i] = v.w;
    }
    __syncthreads();
#pragma unroll
    for (int i = 0; i < 64; i += 16) {
        float4 v;
        v.x = tile[rr + i][c4 + 0];
        v.y = tile[rr + i][c4 + 1];
        v.z = tile[rr + i][c4 + 2];
        v.w = tile[rr + i][c4 + 3];
        *reinterpret_cast<float4*>(
            WT + (size_t)(k0 + rr + i) * DIM + o0 + c4) = v;
    }
}

__global__ __launch_bounds__(NT, 6)
void snn_lif_kernel(const float* __restrict__ x,
                    const float* __restrict__ WT,
                    float* __restrict__ out)
{
    __shared__ __align__(16) float wlds[(KT * ROWB) / 4];

    const int tid  = threadIdx.x;
    const int lane = tid & 63;
    const int w    = tid >> 6;
    const int bl   = w & 1;
    const int tq   = w >> 1;
    const int o_blk = blockIdx.x & 7;
    const int b_blk = blockIdx.x >> 3;
    const int b  = b_blk * B_TILE + bl;
    const int o0 = o_blk * O_TILE;

    double acc[5][4];
#pragma unroll
    for (int tt = 0; tt < 5; ++tt)
#pragma unroll
        for (int u = 0; u < 4; ++u) acc[tt][u] = 0.0;

    const int kl = lane & 31;
    float xr[5];
#pragma unroll
    for (int m = 0; m < 5; ++m)
        xr[m] = x[((size_t)(tq * 5 + m) * BATCH + b) * DIM + kl];

    const char*   gb   = (const char*)wlds + (lane << 4);
    LDS_AS char*  ldsb = (LDS_AS char*)wlds;
    const float*  wsrc = WT + o0 + (lane << 2);

    for (int kt = 0; kt < NSLAB; ++kt) {
        const int k0 = kt * KT;
        __syncthreads();
#pragma unroll
        for (int it = 0; it < 4; ++it) {
            const int r = w + it * 8;
            __builtin_amdgcn_global_load_lds(
                (const GLOBAL_AS void*)(wsrc + (size_t)(k0 + r) * DIM),
                (LDS_AS void*)(ldsb + r * ROWB), 16, 0, 0);
        }
        unsigned mk[5];
#pragma unroll
        for (int m = 0; m < 5; ++m)
            mk[m] = (unsigned)__ballot(xr[m] != 0.0f);
        __syncthreads();
        if (kt + 1 < NSLAB) {
            const int k1 = k0 + KT;
#pragma unroll
            for (int m = 0; m < 5; ++m)
                xr[m] = x[((size_t)(tq * 5 + m) * BATCH + b) * DIM + k1 + kl];
        }
#pragma unroll
        for (int m = 0; m < 5; ++m) {
            unsigned msk = mk[m];
            while (msk & (msk - 1)) {
                const int r0 = __builtin_ctz(msk); msk &= msk - 1;
                const int r1 = __builtin_ctz(msk); msk &= msk - 1;
                const float4 va = *reinterpret_cast<const float4*>(gb + (r0 << 10));
                const float4 vb = *reinterpret_cast<const float4*>(gb + (r1 << 10));
                acc[m][0] += (double)va.x; acc[m][1] += (double)va.y;
                acc[m][2] += (double)va.z; acc[m][3] += (double)va.w;
                acc[m][0] += (double)vb.x; acc[m][1] += (double)vb.y;
                acc[m][2] += (double)vb.z; acc[m][3] += (double)vb.w;
            }
            if (msk) {
                const int r = __builtin_ctz(msk);
                const float4 wv = *reinterpret_cast<const float4*>(gb + (r << 10));
                acc[m][0] += (double)wv.x; acc[m][1] += (double)wv.y;
                acc[m][2] += (double)wv.z; acc[m][3] += (double)wv.w;
            }
        }
    }

    const double A_M = 1.0 - 1.0 / 20.0;
    const double DTM = 1.0 / 20.0;
    const double A_S = 1.0 - 1.0 / 5.0;

    __syncthreads();
    double2* hand = reinterpret_cast<double2*>(wlds);
    const int hbase = bl * 256 + (lane << 2);
    const size_t obase = (size_t)o0 + (lane << 2);

    for (int seg = 0; seg < 4; ++seg) {
        if (tq == seg) {
            double V[4], I[4];
            if (seg == 0) {
#pragma unroll
                for (int u = 0; u < 4; ++u) { V[u] = 0.0; I[u] = 0.0; }
            } else {
#pragma unroll
                for (int u = 0; u < 4; ++u) {
                    const double2 h = hand[hbase + u];
                    V[u] = h.x; I[u] = h.y;
                }
            }
#pragma unroll
            for (int tt = 0; tt < 5; ++tt) {
                const int t = seg * 5 + tt;
                float4 s;
                float* sp = &s.x;
#pragma unroll
                for (int u = 0; u < 4; ++u) {
                    V[u] = A_M * V[u] + DTM * I[u];
                    float sv = 0.0f;
                    if (V[u] >= 1.0) { sv = 1.0f; V[u] = 0.0; }
                    sp[u] = sv;
                    I[u] = A_S * I[u] + acc[tt][u];
                }
                *reinterpret_cast<float4*>(
                    out + ((size_t)t * BATCH + b) * DIM + obase) = s;
            }
            if (seg < 3) {
#pragma unroll
                for (int u = 0; u < 4; ++u)
                    hand[hbase + u] = make_double2(V[u], I[u]);
            }
        }
        __syncthreads();
    }
}

// ============================== host ==============================

extern "C" void kernel_launch(void* const* d_in, const int* in_sizes, int n_in,
                              void* d_out, int out_size, void* d_ws, size_t ws_size,
                              hipStream_t stream) {
    const float* x = (const float*)d_in[0];   // [20, 512, 2048] spikes
    const float* W = (const float*)d_in[1];   // [2048, 2048]
    float* out = (float*)d_out;               // [20, 512, 2048]
    char* wsb = (char*)d_ws;

    // choose the largest o-chunk whose int16 C planes fit in ws
    // need(no) = C_OFF + 4 * 10240 * no * 2 bytes
    int no = 0, shift = 0;
    if      (ws_size >= C_OFF + 81920ULL * 2048) { no = 2048; shift = 9; }
    else if (ws_size >= C_OFF + 81920ULL * 1024) { no = 1024; shift = 8; }
    else if (ws_size >= C_OFF + 81920ULL * 512)  { no = 512;  shift = 7; }
    else if (ws_size >= C_OFF + 81920ULL * 256)  { no = 256;  shift = 6; }
    else if (ws_size >= C_OFF + 81920ULL * 128)  { no = 128;  shift = 5; }

    if (no) {
        // exact i8-MFMA path (R15 gemm; single-shot when no=2048)
        prep_x_kernel<<<2560, 256, 0, stream>>>(x, wsb);
        prep_w_kernel<<<512, 256, 0, stream>>>(W, wsb);
        short* cp = (short*)(wsb + C_OFF);
        const int ntc_cnt = no / 128;
        for (int nt0 = 0; nt0 < 16; nt0 += ntc_cnt) {
            gemm_i8_kernel<<<4 * ntc_cnt * 80, 256, 0, stream>>>(
                (const char*)wsb, cp, nt0, ntc_cnt, no);
            lif_kernel<<<no / 2, 256, 0, stream>>>(
                (const short*)cp, out, nt0 * 128, no, shift);
        }
    } else {
        // fallback: R10 sparse-gather pipeline (known-good, 580 us)
        float* WT = (float*)d_ws;
        dim3 tb(256);
        dim3 tg(DIM / 64, DIM / 64);
        transpose_kernel<<<tg, tb, 0, stream>>>(W, WT);
        const int grid = (BATCH / B_TILE) * (DIM / O_TILE);
        snn_lif_kernel<<<grid, NT, 0, stream>>>(x, WT, out);
    }
}

// Round 19
// 327.955 us; speedup vs baseline: 1.2197x; 1.0307x over previous
//
#include <hip/hip_runtime.h>
#include <stdint.h>

// SpikingLinearLayer: 20-step LIF over [512 batch, 2048 out] driven by
// binary (10% dense) input spikes x[20,512,2048] through W[2048,2048].
//
// EXACT i8-MFMA path (validated absmax 0.0 in R14-R18): W -> 4 limbs of
// q = round(W*2^31) (3 balanced base-256 digits + top); x in {0,1}.
// C = (sum_j 256^j C_j) * 2^-31, C_j exact int32 i8 GEMMs; int64
// recombine + fp64 scale exact. QUANTIZATION FROZEN (3-limb => O(1)
// spike flips; do not reduce).
//
// Gemm history: R15 dbuf DMA 128x128 -> 160us @47%; R17 swizzle
// reverted (LLC temporal locality beats XCD placement); R18 single-shot
// -> 150us @53%, delivery 17.5 TB/s == the LLC practical ceiling
// (16.4 and 17.5 measured on the same wall). MFMA floor 78us. Only
// remaining lever: staged BYTES.
//
// R19: 256x128 tiles (A = two stacked xq tiles, 512 thr / 8 waves):
// staged 2.62 -> 2.01 GB (-23%) at the same delivery wall -> ~115us
// transfer. Keeps 16 waves/CU (2 blk x 8 waves, LDS 96 KB, acc 64
// VGPR/wave, cap 128 via launch_bounds(512,4) -- no spill, R7 lesson).
// LDS tile layout / k-window / epilogue identical to validated R15.
// Plus: prep_w writes via LDS re-pack (linear 8 KB plane stores, kills
// ~4x write amplification of scattered uchar4).

#define STEPS  20
#define BATCH  512
#define DIM    2048

// ---- ws layout (MFMA path)
#define XQ_OFF   0ULL
#define WQ_OFF   20971520ULL          // xq: 80*32*8192
#define C_OFF    37748736ULL          // + wq: 4*16*32*8192

#define GLOBAL_AS __attribute__((address_space(1)))
#define LDS_AS    __attribute__((address_space(3)))

typedef int v4i  __attribute__((ext_vector_type(4)));
typedef int v16i __attribute__((ext_vector_type(16)));

// ============================ MFMA path ============================

// xq[mt<80][kc<32][w<4][mm<128][16] : byte = (x[m][k]!=0)
//   m = mt*128+mm, k = kc*64 + w*16 + j   (m = t*512+b natural order)
__global__ __launch_bounds__(256)
void prep_x_kernel(const float* __restrict__ x, char* __restrict__ wsb)
{
    const int bid = blockIdx.x;           // bid = mt*32 + kc
    const int kc = bid & 31, mt = bid >> 5;
    const int tid = threadIdx.x;
    char* outb = wsb + (size_t)bid * 8192;
#pragma unroll
    for (int it = 0; it < 8; ++it) {
        const int idx = it * 256 + tid;
        const int mm = idx >> 4;
        const int kk4 = (idx & 15) << 2;
        const float4 v = *reinterpret_cast<const float4*>(
            x + (size_t)(mt * 128 + mm) * DIM + kc * 64 + kk4);
        uchar4 o;
        o.x = (v.x != 0.0f); o.y = (v.y != 0.0f);
        o.z = (v.z != 0.0f); o.w = (v.w != 0.0f);
        *reinterpret_cast<uchar4*>(
            outb + (((kk4 >> 4) * 128 + mm) << 4) + (kk4 & 15)) = o;
    }
}

// wq[limb<4][nt<16][kc<32][w<4][nn<128][16] :
//   byte = digit_limb(round(W[o][k]*2^31)), o = nt*128+nn, k = kc*64+w*16+j
// R19: digits staged in LDS, planes written out linearly (coalesced).
__global__ __launch_bounds__(256)
void prep_w_kernel(const float* __restrict__ W, char* __restrict__ wsb)
{
    __shared__ __align__(16) char pl[4][8192];
    const int bid = blockIdx.x;           // bid = nt*32 + kc
    const int kc = bid & 31, nt = bid >> 5;
    const int tid = threadIdx.x;
    char* wqb = wsb + WQ_OFF;
#pragma unroll
    for (int it = 0; it < 8; ++it) {
        const int idx = it * 256 + tid;
        const int nn = idx >> 4;
        const int kk4 = (idx & 15) << 2;
        const float4 v = *reinterpret_cast<const float4*>(
            W + (size_t)(nt * 128 + nn) * DIM + kc * 64 + kk4);
        int dg[4][4];
        const float* vp = &v.x;
#pragma unroll
        for (int c = 0; c < 4; ++c) {
            long long q = __double2ll_rn((double)vp[c] * 2147483648.0);
#pragma unroll
            for (int j = 0; j < 3; ++j) {
                int d = (int)(q & 255);
                if (d >= 128) d -= 256;        // balanced digit
                dg[c][j] = d;
                q = (q - d) >> 8;
            }
            dg[c][3] = (int)q;                 // |.| <= ~97 for |W| < 0.76
        }
        const int sub = (((kk4 >> 4) * 128 + nn) << 4) + (kk4 & 15);
#pragma unroll
        for (int j = 0; j < 4; ++j) {
            uchar4 o;
            o.x = (unsigned char)(dg[0][j] & 255);
            o.y = (unsigned char)(dg[1][j] & 255);
            o.z = (unsigned char)(dg[2][j] & 255);
            o.w = (unsigned char)(dg[3][j] & 255);
            *reinterpret_cast<uchar4*>(&pl[j][sub]) = o;
        }
    }
    __syncthreads();
#pragma unroll
    for (int j = 0; j < 4; ++j) {
        char* dst = wqb + ((size_t)((j * 16 + nt) * 32 + kc)) * 8192;
#pragma unroll
        for (int rep = 0; rep < 2; ++rep) {
            const int off = (rep * 256 + tid) * 16;
            *reinterpret_cast<int4*>(dst + off) =
                *reinterpret_cast<const int4*>(&pl[j][off]);
        }
    }
}

// C_j[m][o_local] int16 planes. R19 tile: 256x128 per limb, 512 thr /
// 8 waves (wy = w&3 -> m-sub of 64, wx = w>>2 -> n-sub of 64), each
// wave 2x2 of 32x32x32 i8 mfma. A = two stacked xq tiles (16 KB) + B
// 8 KB per kc; double-buffered DMA, 1 barrier per kc. Grid: limb slow,
// ntc mid, mtb FAST (B-tile sharers consecutive; xq LLC-resident).
__global__ __launch_bounds__(512, 4)
void gemm_i8_kernel(const char* __restrict__ wsb_c, short* __restrict__ cp,
                    int nt0, int ntc_cnt, int no)
{
    __shared__ __align__(16) char lds[2][24576];  // [buf][A0 8K|A1 8K|B 8K]

    const int bid = blockIdx.x;           // mtb fastest, ntc mid, limb slow
    const int mtb = bid % 40;
    const int rest = bid / 40;
    const int ntc = rest % ntc_cnt;
    const int limb = rest / ntc_cnt;

    const int tid = threadIdx.x;
    const int lane = tid & 63, w = tid >> 6;   // 8 waves
    const int kh = lane >> 5, ln = lane & 31;
    const int wy = w & 3, wx = w >> 2;

    const char* abase0 = wsb_c + XQ_OFF + ((size_t)(2 * mtb) * 32) * 8192;
    const char* abase1 = abase0 + (size_t)32 * 8192;
    const char* bbase = wsb_c + WQ_OFF
        + ((size_t)((limb * 16 + nt0 + ntc) * 32)) * 8192;

    // A read: tile (wy>>1), 64-row block (wy&1) within 128
    const int atile = (wy >> 1) * 8192;
    const int aoffl = ((kh * 128) + (wy & 1) * 64 + ln) << 4;
    const int boff  = ((kh * 128) + wx * 64 + ln) << 4;
    const int stg = w * 1024 + (lane << 4);   // wave's 1 KB DMA slot

    v16i acc00, acc01, acc10, acc11;
#pragma unroll
    for (int r = 0; r < 16; ++r) {
        acc00[r] = 0; acc01[r] = 0; acc10[r] = 0; acc11[r] = 0;
    }

    LDS_AS char* l0 = (LDS_AS char*)(&lds[0][0]);
    LDS_AS char* l1 = (LDS_AS char*)(&lds[1][0]);

    // prologue: stage kc=0 into buf0 (A0, A1, B: 1 KB per wave each)
    __builtin_amdgcn_global_load_lds(
        (const GLOBAL_AS void*)(abase0 + stg),
        (LDS_AS void*)(l0 + w * 1024), 16, 0, 0);
    __builtin_amdgcn_global_load_lds(
        (const GLOBAL_AS void*)(abase1 + stg),
        (LDS_AS void*)(l0 + 8192 + w * 1024), 16, 0, 0);
    __builtin_amdgcn_global_load_lds(
        (const GLOBAL_AS void*)(bbase + stg),
        (LDS_AS void*)(l0 + 16384 + w * 1024), 16, 0, 0);

    for (int kc = 0; kc < 32; ++kc) {
        __syncthreads();   // drains prefetch for kc (issued one iter ago)
        const int cur = kc & 1;
        if (kc + 1 < 32) {
            LDS_AS char* ldst = (kc & 1) ? l0 : l1;
            const size_t src = (size_t)(kc + 1) * 8192 + stg;
            __builtin_amdgcn_global_load_lds(
                (const GLOBAL_AS void*)(abase0 + src),
                (LDS_AS void*)(ldst + w * 1024), 16, 0, 0);
            __builtin_amdgcn_global_load_lds(
                (const GLOBAL_AS void*)(abase1 + src),
                (LDS_AS void*)(ldst + 8192 + w * 1024), 16, 0, 0);
            __builtin_amdgcn_global_load_lds(
                (const GLOBAL_AS void*)(bbase + src),
                (LDS_AS void*)(ldst + 16384 + w * 1024), 16, 0, 0);
        }
        const char* A = &lds[cur][atile];
        const char* B = &lds[cur][16384];
#pragma unroll
        for (int s = 0; s < 2; ++s) {
            const v4i a0 = *reinterpret_cast<const v4i*>(A + aoffl + s * 4096);
            const v4i a1 = *reinterpret_cast<const v4i*>(A + aoffl + 512 + s * 4096);
            const v4i b0 = *reinterpret_cast<const v4i*>(B + boff + s * 4096);
            const v4i b1 = *reinterpret_cast<const v4i*>(B + boff + 512 + s * 4096);
            acc00 = __builtin_amdgcn_mfma_i32_32x32x32_i8(a0, b0, acc00, 0, 0, 0);
            acc01 = __builtin_amdgcn_mfma_i32_32x32x32_i8(a0, b1, acc01, 0, 0, 0);
            acc10 = __builtin_amdgcn_mfma_i32_32x32x32_i8(a1, b0, acc10, 0, 0, 0);
            acc11 = __builtin_amdgcn_mfma_i32_32x32x32_i8(a1, b1, acc11, 0, 0, 0);
        }
    }

    // epilogue: C/D layout col=lane&31, row=(r&3)+8*(r>>2)+4*(lane>>5)
    short* cpl = cp + (size_t)limb * 10240 * no;
    const int m_base = mtb * 256 + wy * 64;
    const int o_base = ntc * 128 + wx * 64 + ln;
#pragma unroll
    for (int r = 0; r < 16; ++r) {
        const int row = (r & 3) + ((r >> 2) << 3) + (kh << 2);
        const size_t m0 = (size_t)(m_base + row) * no;
        const size_t m1 = (size_t)(m_base + 32 + row) * no;
        cpl[m0 + o_base]      = (short)acc00[r];
        cpl[m0 + o_base + 32] = (short)acc01[r];
        cpl[m1 + o_base]      = (short)acc10[r];
        cpl[m1 + o_base + 32] = (short)acc11[r];
    }
}

// LIF scan: exact int64 recombine of 4 int16 limb planes, fp64 scale
// by 2^-31 (exact), reference op order.
__global__ __launch_bounds__(256)
void lif_kernel(const short* __restrict__ cp, float* __restrict__ out,
                int o0, int no, int shift)
{
    const int g = blockIdx.x * 256 + threadIdx.x;
    const int b = g >> shift;                  // shift = log2(no/4)
    const int oq = g & ((1 << shift) - 1);
    const int o_local = oq << 2;
    const size_t plane = (size_t)10240 * no;

    const double A_M = 1.0 - 1.0 / 20.0;   // 0.95
    const double DTM = 1.0 / 20.0;         // 0.05
    const double A_S = 1.0 - 1.0 / 5.0;    // 0.8
    double V[4], I[4];
#pragma unroll
    for (int u = 0; u < 4; ++u) { V[u] = 0.0; I[u] = 0.0; }

#pragma unroll
    for (int t = 0; t < STEPS; ++t) {
        const size_t ix = (size_t)(t * BATCH + b) * no + o_local;
        const short4 c0 = *reinterpret_cast<const short4*>(cp + ix);
        const short4 c1 = *reinterpret_cast<const short4*>(cp + plane + ix);
        const short4 c2 = *reinterpret_cast<const short4*>(cp + 2 * plane + ix);
        const short4 c3 = *reinterpret_cast<const short4*>(cp + 3 * plane + ix);
        const short* p0 = &c0.x; const short* p1 = &c1.x;
        const short* p2 = &c2.x; const short* p3 = &c3.x;
        float4 s;
        float* sp = &s.x;
#pragma unroll
        for (int u = 0; u < 4; ++u) {
            const long long tot = (long long)p0[u]
                + ((long long)p1[u] << 8)
                + ((long long)p2[u] << 16)
                + ((long long)p3[u] << 24);
            const double val = (double)tot * 4.6566128730773926e-10; // 2^-31
            V[u] = A_M * V[u] + DTM * I[u];
            float sv = 0.0f;
            if (V[u] >= 1.0) { sv = 1.0f; V[u] = 0.0; }
            sp[u] = sv;
            I[u] = A_S * I[u] + val;
        }
        *reinterpret_cast<float4*>(
            out + (size_t)(t * BATCH + b) * DIM + o0 + o_local) = s;
    }
}

// ===================== fallback (R10 sparse path) =====================

#define B_TILE 2
#define O_TILE 256
#define NT     512
#define KT     32
#define NSLAB  (DIM / KT)
#define ROWB   1024

__global__ __launch_bounds__(256)
void transpose_kernel(const float* __restrict__ W, float* __restrict__ WT)
{
    __shared__ float tile[64][65];
    const int tid = threadIdx.x;
    const int c4 = (tid & 15) * 4;
    const int rr = tid >> 4;
    const int k0 = blockIdx.x * 64, o0 = blockIdx.y * 64;
#pragma unroll
    for (int i = 0; i < 64; i += 16) {
        const float4 v = *reinterpret_cast<const float4*>(
            W + (size_t)(o0 + rr + i) * DIM + k0 + c4);
        tile[c4 + 0][rr + i] = v.x;
        tile[c4 + 1][rr + i] = v.y;
        tile[c4 + 2][rr + i] = v.z;
        tile[c4 + 3][rr + i] = v.w;
    }
    __syncthreads();
#pragma unroll
    for (int i = 0; i < 64; i += 16) {
        float4 v;
        v.x = tile[rr + i][c4 + 0];
        v.y = tile[rr + i][c4 + 1];
        v.z = tile[rr + i][c4 + 2];
        v.w = tile[rr + i][c4 + 3];
        *reinterpret_cast<float4*>(
            WT + (size_t)(k0 + rr + i) * DIM + o0 + c4) = v;
    }
}

__global__ __launch_bounds__(NT, 6)
void snn_lif_kernel(const float* __restrict__ x,
                    const float* __restrict__ WT,
                    float* __restrict__ out)
{
    __shared__ __align__(16) float wlds[(KT * ROWB) / 4];

    const int tid  = threadIdx.x;
    const int lane = tid & 63;
    const int w    = tid >> 6;
    const int bl   = w & 1;
    const int tq   = w >> 1;
    const int o_blk = blockIdx.x & 7;
    const int b_blk = blockIdx.x >> 3;
    const int b  = b_blk * B_TILE + bl;
    const int o0 = o_blk * O_TILE;

    double acc[5][4];
#pragma unroll
    for (int tt = 0; tt < 5; ++tt)
#pragma unroll
        for (int u = 0; u < 4; ++u) acc[tt][u] = 0.0;

    const int kl = lane & 31;
    float xr[5];
#pragma unroll
    for (int m = 0; m < 5; ++m)
        xr[m] = x[((size_t)(tq * 5 + m) * BATCH + b) * DIM + kl];

    const char*   gb   = (const char*)wlds + (lane << 4);
    LDS_AS char*  ldsb = (LDS_AS char*)wlds;
    const float*  wsrc = WT + o0 + (lane << 2);

    for (int kt = 0; kt < NSLAB; ++kt) {
        const int k0 = kt * KT;
        __syncthreads();
#pragma unroll
        for (int it = 0; it < 4; ++it) {
            const int r = w + it * 8;
            __builtin_amdgcn_global_load_lds(
                (const GLOBAL_AS void*)(wsrc + (size_t)(k0 + r) * DIM),
                (LDS_AS void*)(ldsb + r * ROWB), 16, 0, 0);
        }
        unsigned mk[5];
#pragma unroll
        for (int m = 0; m < 5; ++m)
            mk[m] = (unsigned)__ballot(xr[m] != 0.0f);
        __syncthreads();
        if (kt + 1 < NSLAB) {
            const int k1 = k0 + KT;
#pragma unroll
            for (int m = 0; m < 5; ++m)
                xr[m] = x[((size_t)(tq * 5 + m) * BATCH + b) * DIM + k1 + kl];
        }
#pragma unroll
        for (int m = 0; m < 5; ++m) {
            unsigned msk = mk[m];
            while (msk & (msk - 1)) {
                const int r0 = __builtin_ctz(msk); msk &= msk - 1;
                const int r1 = __builtin_ctz(msk); msk &= msk - 1;
                const float4 va = *reinterpret_cast<const float4*>(gb + (r0 << 10));
                const float4 vb = *reinterpret_cast<const float4*>(gb + (r1 << 10));
                acc[m][0] += (double)va.x; acc[m][1] += (double)va.y;
                acc[m][2] += (double)va.z; acc[m][3] += (double)va.w;
                acc[m][0] += (double)vb.x; acc[m][1] += (double)vb.y;
                acc[m][2] += (double)vb.z; acc[m][3] += (double)vb.w;
            }
            if (msk) {
                const int r = __builtin_ctz(msk);
                const float4 wv = *reinterpret_cast<const float4*>(gb + (r << 10));
                acc[m][0] += (double)wv.x; acc[m][1] += (double)wv.y;
                acc[m][2] += (double)wv.z; acc[m][3] += (double)wv.w;
            }
        }
    }

    const double A_M = 1.0 - 1.0 / 20.0;
    const double DTM = 1.0 / 20.0;
    const double A_S = 1.0 - 1.0 / 5.0;

    __syncthreads();
    double2* hand = reinterpret_cast<double2*>(wlds);
    const int hbase = bl * 256 + (lane << 2);
    const size_t obase = (size_t)o0 + (lane << 2);

    for (int seg = 0; seg < 4; ++seg) {
        if (tq == seg) {
            double V[4], I[4];
            if (seg == 0) {
#pragma unroll
                for (int u = 0; u < 4; ++u) { V[u] = 0.0; I[u] = 0.0; }
            } else {
#pragma unroll
                for (int u = 0; u < 4; ++u) {
                    const double2 h = hand[hbase + u];
                    V[u] = h.x; I[u] = h.y;
                }
            }
#pragma unroll
            for (int tt = 0; tt < 5; ++tt) {
                const int t = seg * 5 + tt;
                float4 s;
                float* sp = &s.x;
#pragma unroll
                for (int u = 0; u < 4; ++u) {
                    V[u] = A_M * V[u] + DTM * I[u];
                    float sv = 0.0f;
                    if (V[u] >= 1.0) { sv = 1.0f; V[u] = 0.0; }
                    sp[u] = sv;
                    I[u] = A_S * I[u] + acc[tt][u];
                }
                *reinterpret_cast<float4*>(
                    out + ((size_t)t * BATCH + b) * DIM + obase) = s;
            }
            if (seg < 3) {
#pragma unroll
                for (int u = 0; u < 4; ++u)
                    hand[hbase + u] = make_double2(V[u], I[u]);
            }
        }
        __syncthreads();
    }
}

// ============================== host ==============================

extern "C" void kernel_launch(void* const* d_in, const int* in_sizes, int n_in,
                              void* d_out, int out_size, void* d_ws, size_t ws_size,
                              hipStream_t stream) {
    const float* x = (const float*)d_in[0];   // [20, 512, 2048] spikes
    const float* W = (const float*)d_in[1];   // [2048, 2048]
    float* out = (float*)d_out;               // [20, 512, 2048]
    char* wsb = (char*)d_ws;

    // choose the largest o-chunk whose int16 C planes fit in ws
    // need(no) = C_OFF + 4 * 10240 * no * 2 bytes
    int no = 0, shift = 0;
    if      (ws_size >= C_OFF + 81920ULL * 2048) { no = 2048; shift = 9; }
    else if (ws_size >= C_OFF + 81920ULL * 1024) { no = 1024; shift = 8; }
    else if (ws_size >= C_OFF + 81920ULL * 512)  { no = 512;  shift = 7; }
    else if (ws_size >= C_OFF + 81920ULL * 256)  { no = 256;  shift = 6; }
    else if (ws_size >= C_OFF + 81920ULL * 128)  { no = 128;  shift = 5; }

    if (no) {
        // exact i8-MFMA path (R19 256x128 gemm; single-shot at no=2048)
        prep_x_kernel<<<2560, 256, 0, stream>>>(x, wsb);
        prep_w_kernel<<<512, 256, 0, stream>>>(W, wsb);
        short* cp = (short*)(wsb + C_OFF);
        const int ntc_cnt = no / 128;
        for (int nt0 = 0; nt0 < 16; nt0 += ntc_cnt) {
            gemm_i8_kernel<<<40 * ntc_cnt * 4, 512, 0, stream>>>(
                (const char*)wsb, cp, nt0, ntc_cnt, no);
            lif_kernel<<<no / 2, 256, 0, stream>>>(
                (const short*)cp, out, nt0 * 128, no, shift);
        }
    } else {
        // fallback: R10 sparse-gather pipeline (known-good, 580 us)
        float* WT = (float*)d_ws;
        dim3 tb(256);
        dim3 tg(DIM / 64, DIM / 64);
        transpose_kernel<<<tg, tb, 0, stream>>>(W, WT);
        const int grid = (BATCH / B_TILE) * (DIM / O_TILE);
        snn_lif_kernel<<<grid, NT, 0, stream>>>(x, WT, out);
    }
}